// Round 3
// baseline (606.744 us; speedup 1.0000x reference)
//
#include <hip/hip_runtime.h>

// B=8192, T=240, C=16, DAYS=STRIDE=10 -> W=24 windows tiling T exactly.
// Row r reads contiguous x[r*160 .. r*160+159]. 320 output channels:
// [corr(120), cov(120), std(16), zscore(16), ret(16), decay(16), mean(16)].
#define NROWS   196608
#define NTILES_TOTAL 12288    // 196608 rows / 16 rows-per-tile
#define OUTC    320
#define R_      16            // rows per LDS tile
#define WSTRIDE 164           // win LDS row stride (floats), float4-aligned
#define CSTRIDE 121           // cov LDS row stride
#define MSTRIDE 17            // mean/std LDS row stride
#define EPS_F   1e-8f
#define EPS_BN  1e-5f

// LDS carve (floats): win 16*164=2624 | mn 16*17=272 | sd 272 | cv 16*121=1936 | ex 640
#define L_WIN 0
#define L_MN  2624
#define L_SD  2896
#define L_CV  3168
#define L_EX  5104
#define L_TOT 5744            // 22976 B

// pair p -> packed (i<<4)|j for triu_indices(16, k=1), row-major
__device__ const unsigned char PIJ[120] = {
    0x01,0x02,0x03,0x04,0x05,0x06,0x07,0x08,0x09,0x0A,0x0B,0x0C,0x0D,0x0E,0x0F,
    0x12,0x13,0x14,0x15,0x16,0x17,0x18,0x19,0x1A,0x1B,0x1C,0x1D,0x1E,0x1F,
    0x23,0x24,0x25,0x26,0x27,0x28,0x29,0x2A,0x2B,0x2C,0x2D,0x2E,0x2F,
    0x34,0x35,0x36,0x37,0x38,0x39,0x3A,0x3B,0x3C,0x3D,0x3E,0x3F,
    0x45,0x46,0x47,0x48,0x49,0x4A,0x4B,0x4C,0x4D,0x4E,0x4F,
    0x56,0x57,0x58,0x59,0x5A,0x5B,0x5C,0x5D,0x5E,0x5F,
    0x67,0x68,0x69,0x6A,0x6B,0x6C,0x6D,0x6E,0x6F,
    0x78,0x79,0x7A,0x7B,0x7C,0x7D,0x7E,0x7F,
    0x89,0x8A,0x8B,0x8C,0x8D,0x8E,0x8F,
    0x9A,0x9B,0x9C,0x9D,0x9E,0x9F,
    0xAB,0xAC,0xAD,0xAE,0xAF,
    0xBC,0xBD,0xBE,0xBF,
    0xCD,0xCE,0xCF,
    0xDE,0xDF,
    0xEF
};

// MODE=0: stats pass. dst = part1[block][640] (sum[320] | sumsq[320]), coalesced.
//         Each block processes `ntiles` consecutive tiles (ntiles=1 preferred).
// MODE=1: apply pass. dst = output; ab = {scale[320], shift[320]}; ntiles=1.
template<int MODE>
__global__ __launch_bounds__(256)
void fe_kernel(const float* __restrict__ x, float* __restrict__ dst,
               const float* __restrict__ ab, int ntiles) {
    __shared__ __align__(16) float lds[L_TOT];
    float* win = lds + L_WIN;
    float* mn  = lds + L_MN;
    float* sd  = lds + L_SD;
    float* cv  = lds + L_CV;
    float* ex  = lds + L_EX;

    const int t = threadIdx.x;

    float sacc[20], sacc2[20];
    if (MODE == 0) {
#pragma unroll
        for (int k = 0; k < 20; ++k) { sacc[k] = 0.f; sacc2[k] = 0.f; }
    } else {
        // preload scale/shift (640 floats) into LDS
        ex[t] = ab[t];
        ex[t + 256] = ab[t + 256];
        if (t < 128) ex[t + 512] = ab[t + 512];
    }

    for (int tt = 0; tt < ntiles; ++tt) {
        const int tile = blockIdx.x * ntiles + tt;
        const float4* src = reinterpret_cast<const float4*>(x) + (size_t)tile * (R_ * 40);

        __syncthreads();   // previous iteration readers done / ex visible
        // ---- stage 16 rows x 160 floats, coalesced float4 ----
#pragma unroll
        for (int k = 0; k < 3; ++k) {
            int q = t + k * 256;
            if (q < 640) {
                float4 v = src[q];
                int row = q / 40, pos = q % 40;
                reinterpret_cast<float4*>(win)[row * (WSTRIDE / 4) + pos] = v;
            }
        }
        __syncthreads();

        // ---- mean/std per (row, channel): 256 tasks ----
        {
            int c = t & 15, r = t >> 4;
            const float* wr = win + r * WSTRIDE + c;
            float s = 0.f;
#pragma unroll
            for (int d = 0; d < 10; ++d) s += wr[d * 16];
            float m = s * 0.1f;
            float v = 0.f;
#pragma unroll
            for (int d = 0; d < 10; ++d) { float dx = wr[d * 16] - m; v += dx * dx; }
            mn[r * MSTRIDE + c] = m;
            sd[r * MSTRIDE + c] = sqrtf(v * 0.1f);
        }
        __syncthreads();

        // ---- cov per (row, pair): 16*120 = 1920 tasks ----
#pragma unroll
        for (int k = 0; k < 8; ++k) {
            int task = t + k * 256;
            if (task < 1920) {
                int r = task & 15, p = task >> 4;
                int pj = PIJ[p];
                int i = pj >> 4, j = pj & 15;
                float mi = mn[r * MSTRIDE + i], mj = mn[r * MSTRIDE + j];
                const float* wr = win + r * WSTRIDE;
                float s = 0.f;
#pragma unroll
                for (int d = 0; d < 10; ++d)
                    s += (wr[d * 16 + i] - mi) * (wr[d * 16 + j] - mj);
                cv[r * CSTRIDE + p] = s * 0.1f;
            }
        }
        __syncthreads();

        // ---- outputs: 16*320 = 5120 elements, thread <-> element ----
#pragma unroll
        for (int k = 0; k < 20; ++k) {
            int flat = t + k * 256;
            int r = flat / 320, c = flat % 320;
            float v;
            if (c < 240) {
                int p = (c < 120) ? c : (c - 120);
                float cvv = cv[r * CSTRIDE + p];
                if (c < 120) {
                    int pj = PIJ[p];
                    int i = pj >> 4, j = pj & 15;
                    v = cvv / (sd[r * MSTRIDE + i] * sd[r * MSTRIDE + j] + EPS_F);
                } else {
                    v = cvv;
                }
            } else {
                int cc = c & 15;
                int cls = (c - 240) >> 4;   // 0:std 1:zscore 2:ret 3:decay 4:mean
                const float* wr = win + r * WSTRIDE + cc;
                float m = mn[r * MSTRIDE + cc], s = sd[r * MSTRIDE + cc];
                if (cls == 0)      v = s;
                else if (cls == 1) v = m / (s + EPS_F);
                else if (cls == 2) v = wr[144] / wr[0] - 1.0f;
                else if (cls == 3) {
                    float a = 0.f;
#pragma unroll
                    for (int d = 0; d < 10; ++d)
                        a += wr[d * 16] * ((float)(d + 1) * (1.0f / 55.0f));
                    v = a;
                } else v = m;
            }
            if (MODE == 1) {
                dst[(size_t)tile * (R_ * OUTC) + flat] = v * ex[c] + ex[OUTC + c];
            } else {
                sacc[k] += v;
                sacc2[k] += v * v;
            }
        }
    }

    if (MODE == 0) {
        // Per-wave LDS bins (no cross-wave races, 3 syncs total), then
        // coalesced per-block partial write: part1[block][640].
        __syncthreads();                        // done reading win/cv
        for (int idx = t; idx < 2560; idx += 256) lds[idx] = 0.f;
        __syncthreads();
        float* wb = lds + (t >> 6) * 640;       // this wave's bin
#pragma unroll
        for (int k = 0; k < 20; ++k) {
            int c = (t + k * 256) % 320;        // distinct per lane within wave
            wb[c]       += sacc[k];
            wb[c + 320] += sacc2[k];
        }
        __syncthreads();
        for (int idx = t; idx < 640; idx += 256) {
            float s = lds[idx] + lds[640 + idx] + lds[1280 + idx] + lds[1920 + idx];
            dst[(size_t)blockIdx.x * 640 + idx] = s;
        }
    }
}

// Stage-2 reduce: 64 blocks; block b sums rows [b*rows, (b+1)*rows) of
// part1[nb][640] into part2[b][640]. Coalesced (lanes = consecutive v).
__global__ __launch_bounds__(256)
void reduce1_kernel(const float* __restrict__ part1, float* __restrict__ part2,
                    int nb) {
    const int rows = nb >> 6;
    const int b = blockIdx.x;
    for (int v = threadIdx.x; v < 640; v += 256) {
        float s = 0.f;
        const float* p = part1 + (size_t)b * rows * 640 + v;
        for (int r = 0; r < rows; ++r) s += p[(size_t)r * 640];
        part2[(size_t)b * 640 + v] = s;
    }
}

// Final: fp64 reduce of 64 partials per channel -> scale/shift.
__global__ __launch_bounds__(256)
void finalize_kernel(const float* __restrict__ part2,
                     const float* __restrict__ gamma,
                     const float* __restrict__ beta,
                     float* __restrict__ ab) {
    __shared__ double sums[640];
    const int t = threadIdx.x;
    for (int v = t; v < 640; v += 256) {
        double s = 0.0;
        for (int k = 0; k < 64; ++k) s += (double)part2[(size_t)k * 640 + v];
        sums[v] = s;
    }
    __syncthreads();
    for (int c = t; c < 320; c += 256) {
        const double invN = 1.0 / (double)NROWS;
        double m = sums[c] * invN;
        double v = sums[320 + c] * invN - m * m;
        if (v < 0.0) v = 0.0;
        float a = gamma[c] / sqrtf((float)v + EPS_BN);
        ab[c] = a;
        ab[OUTC + c] = beta[c] - (float)m * a;
    }
}

extern "C" void kernel_launch(void* const* d_in, const int* in_sizes, int n_in,
                              void* d_out, int out_size, void* d_ws, size_t ws_size,
                              hipStream_t stream) {
    const float* x     = (const float*)d_in[0];
    const float* gamma = (const float*)d_in[1];
    const float* beta  = (const float*)d_in[2];
    float* out = (float*)d_out;

    // Pick tiles-per-block for the stats pass so partials fit in d_ws.
    // (ws_size is fixed across calls -> same config every call: deterministic.)
    int ntiles = 8;
    for (int nt = 1; nt <= 8; nt <<= 1) {
        size_t nb = NTILES_TOTAL / nt;
        size_t need = nb * 640 * 4 + 64 * 640 * 4 + 640 * 4;
        if (need <= ws_size) { ntiles = nt; break; }
    }
    const int nb = NTILES_TOTAL / ntiles;

    float* part1 = (float*)d_ws;                       // nb*640 floats
    float* part2 = part1 + (size_t)nb * 640;           // 64*640 floats
    float* ab    = part2 + (size_t)64 * 640;           // 640 floats

    fe_kernel<0><<<nb, 256, 0, stream>>>(x, part1, nullptr, ntiles);
    reduce1_kernel<<<64, 256, 0, stream>>>(part1, part2, nb);
    finalize_kernel<<<1, 256, 0, stream>>>(part2, gamma, beta, ab);
    fe_kernel<1><<<NTILES_TOTAL, 256, 0, stream>>>(x, out, ab, 1);
}

// Round 4
// 367.655 us; speedup vs baseline: 1.6503x; 1.6503x over previous
//
#include <hip/hip_runtime.h>

// B=8192, T=240, C=16, DAYS=STRIDE=10 -> W=24 windows tiling T exactly.
// Row r reads contiguous x[r*160 .. r*160+159]. 320 output channels:
// [corr(120), cov(120), std(16), zscore(16), ret(16), decay(16), mean(16)].
#define NROWS   196608
#define NTILES_TOTAL 12288    // 196608 rows / 16 rows-per-tile
#define OUTC    320
#define R_      16            // rows per LDS tile
#define WSTRIDE 164           // win LDS row stride (floats), float4-aligned
#define CSTRIDE 121           // cov LDS row stride
#define MSTRIDE 17            // mean/std LDS row stride
#define EPS_F   1e-8f
#define EPS_BN  1e-5f

// pair p -> packed (i<<4)|j for triu_indices(16, k=1), row-major
__device__ const unsigned char PIJ[120] = {
    0x01,0x02,0x03,0x04,0x05,0x06,0x07,0x08,0x09,0x0A,0x0B,0x0C,0x0D,0x0E,0x0F,
    0x12,0x13,0x14,0x15,0x16,0x17,0x18,0x19,0x1A,0x1B,0x1C,0x1D,0x1E,0x1F,
    0x23,0x24,0x25,0x26,0x27,0x28,0x29,0x2A,0x2B,0x2C,0x2D,0x2E,0x2F,
    0x34,0x35,0x36,0x37,0x38,0x39,0x3A,0x3B,0x3C,0x3D,0x3E,0x3F,
    0x45,0x46,0x47,0x48,0x49,0x4A,0x4B,0x4C,0x4D,0x4E,0x4F,
    0x56,0x57,0x58,0x59,0x5A,0x5B,0x5C,0x5D,0x5E,0x5F,
    0x67,0x68,0x69,0x6A,0x6B,0x6C,0x6D,0x6E,0x6F,
    0x78,0x79,0x7A,0x7B,0x7C,0x7D,0x7E,0x7F,
    0x89,0x8A,0x8B,0x8C,0x8D,0x8E,0x8F,
    0x9A,0x9B,0x9C,0x9D,0x9E,0x9F,
    0xAB,0xAC,0xAD,0xAE,0xAF,
    0xBC,0xBD,0xBE,0xBF,
    0xCD,0xCE,0xCF,
    0xDE,0xDF,
    0xEF
};

// MODE=0: stats pass. dst = part1[block][640] (sum[320] | sumsq[320]), coalesced.
//         Processes NTILES consecutive tiles (compile-time trip count).
// MODE=1: apply pass (NTILES=1). dst = output; ab = {scale[320], shift[320]}.
template<int MODE, int NTILES>
__global__ __launch_bounds__(256)
void fe_kernel(const float* __restrict__ x, float* __restrict__ dst,
               const float* __restrict__ ab) {
    __shared__ __align__(16) float win[R_ * WSTRIDE];   // 10496 B
    __shared__ float mn[R_ * MSTRIDE];                  // 1088 B
    __shared__ float sd[R_ * MSTRIDE];                  // 1088 B
    __shared__ float cv[R_ * CSTRIDE];                  // 7744 B
    __shared__ float ex[2 * OUTC];                      // 2560 B

    const int t = threadIdx.x;

    float sacc[20], sacc2[20];
    if (MODE == 0) {
#pragma unroll
        for (int k = 0; k < 20; ++k) { sacc[k] = 0.f; sacc2[k] = 0.f; }
    } else {
        // preload scale/shift (640 floats) into LDS
        ex[t] = ab[t];
        ex[t + 256] = ab[t + 256];
        if (t < 128) ex[t + 512] = ab[t + 512];
    }

#pragma unroll 1
    for (int tt = 0; tt < NTILES; ++tt) {
        const int tile = blockIdx.x * NTILES + tt;
        const float4* src = reinterpret_cast<const float4*>(x) + (size_t)tile * (R_ * 40);

        __syncthreads();   // previous iteration readers done / ex visible
        // ---- stage 16 rows x 160 floats, coalesced float4 ----
#pragma unroll
        for (int k = 0; k < 3; ++k) {
            int q = t + k * 256;
            if (q < 640) {
                float4 v = src[q];
                int row = q / 40, pos = q % 40;
                reinterpret_cast<float4*>(win)[row * (WSTRIDE / 4) + pos] = v;
            }
        }
        __syncthreads();

        // ---- mean/std per (row, channel): 256 tasks ----
        // r = t&15 (varies fastest) -> within a wave banks hit <=2-way (free).
        {
            int r = t & 15, c = t >> 4;
            const float* wr = win + r * WSTRIDE + c;
            float s = 0.f;
#pragma unroll
            for (int d = 0; d < 10; ++d) s += wr[d * 16];
            float m = s * 0.1f;
            float v = 0.f;
#pragma unroll
            for (int d = 0; d < 10; ++d) { float dx = wr[d * 16] - m; v += dx * dx; }
            mn[r * MSTRIDE + c] = m;
            sd[r * MSTRIDE + c] = sqrtf(v * 0.1f);
        }
        __syncthreads();

        // ---- cov per (row, pair): 16*120 = 1920 tasks ----
#pragma unroll
        for (int k = 0; k < 8; ++k) {
            int task = t + k * 256;
            if (task < 1920) {
                int r = task & 15, p = task >> 4;
                int pj = PIJ[p];
                int i = pj >> 4, j = pj & 15;
                float mi = mn[r * MSTRIDE + i], mj = mn[r * MSTRIDE + j];
                const float* wr = win + r * WSTRIDE;
                float s = 0.f;
#pragma unroll
                for (int d = 0; d < 10; ++d)
                    s += (wr[d * 16 + i] - mi) * (wr[d * 16 + j] - mj);
                cv[r * CSTRIDE + p] = s * 0.1f;
            }
        }
        __syncthreads();

        // ---- outputs: 16*320 = 5120 elements, thread <-> element ----
#pragma unroll
        for (int k = 0; k < 20; ++k) {
            int flat = t + k * 256;
            int r = flat / 320, c = flat % 320;
            float v;
            if (c < 240) {
                int p = (c < 120) ? c : (c - 120);
                float cvv = cv[r * CSTRIDE + p];
                if (c < 120) {
                    int pj = PIJ[p];
                    int i = pj >> 4, j = pj & 15;
                    v = cvv / (sd[r * MSTRIDE + i] * sd[r * MSTRIDE + j] + EPS_F);
                } else {
                    v = cvv;
                }
            } else {
                int cc = c & 15;
                int cls = (c - 240) >> 4;   // 0:std 1:zscore 2:ret 3:decay 4:mean
                const float* wr = win + r * WSTRIDE + cc;
                float m = mn[r * MSTRIDE + cc], s = sd[r * MSTRIDE + cc];
                if (cls == 0)      v = s;
                else if (cls == 1) v = m / (s + EPS_F);
                else if (cls == 2) v = wr[144] / wr[0] - 1.0f;
                else if (cls == 3) {
                    float a = 0.f;
#pragma unroll
                    for (int d = 0; d < 10; ++d)
                        a += wr[d * 16] * ((float)(d + 1) * (1.0f / 55.0f));
                    v = a;
                } else v = m;
            }
            if (MODE == 1) {
                dst[(size_t)tile * (R_ * OUTC) + flat] = v * ex[c] + ex[OUTC + c];
            } else {
                sacc[k] += v;
                sacc2[k] += v * v;
            }
        }
    }

    if (MODE == 0) {
        // Per-wave LDS bins (no cross-wave races), then coalesced per-block
        // partial write part1[block][640]. Bins reuse win's LDS (free after
        // the sync; typed alias of a named array, not a carved blob).
        __syncthreads();                        // everyone done reading win
        float* bins = win;                      // 2560 floats needed, win has 2624
        for (int idx = t; idx < 2560; idx += 256) bins[idx] = 0.f;
        __syncthreads();
        float* wb = bins + (t >> 6) * 640;      // this wave's bin
#pragma unroll
        for (int k = 0; k < 20; ++k) {
            int c = (t + k * 256) % 320;        // distinct per lane within a wave
            wb[c]       += sacc[k];
            wb[c + 320] += sacc2[k];
        }
        __syncthreads();
        for (int idx = t; idx < 640; idx += 256) {
            float s = bins[idx] + bins[640 + idx] + bins[1280 + idx] + bins[1920 + idx];
            dst[(size_t)blockIdx.x * 640 + idx] = s;
        }
    }
}

// Stage-2 reduce: 64 blocks; block b sums rows [b*rows, (b+1)*rows) of
// part1[nb][640] into part2[b][640]. Coalesced (lanes = consecutive v).
__global__ __launch_bounds__(256)
void reduce1_kernel(const float* __restrict__ part1, float* __restrict__ part2,
                    int nb) {
    const int rows = nb >> 6;
    const int b = blockIdx.x;
    for (int v = threadIdx.x; v < 640; v += 256) {
        float s = 0.f;
        const float* p = part1 + (size_t)b * rows * 640 + v;
        for (int r = 0; r < rows; ++r) s += p[(size_t)r * 640];
        part2[(size_t)b * 640 + v] = s;
    }
}

// Final: fp64 reduce of 64 partials per channel -> scale/shift.
__global__ __launch_bounds__(256)
void finalize_kernel(const float* __restrict__ part2,
                     const float* __restrict__ gamma,
                     const float* __restrict__ beta,
                     float* __restrict__ ab) {
    __shared__ double sums[640];
    const int t = threadIdx.x;
    for (int v = t; v < 640; v += 256) {
        double s = 0.0;
        for (int k = 0; k < 64; ++k) s += (double)part2[(size_t)k * 640 + v];
        sums[v] = s;
    }
    __syncthreads();
    for (int c = t; c < 320; c += 256) {
        const double invN = 1.0 / (double)NROWS;
        double m = sums[c] * invN;
        double v = sums[320 + c] * invN - m * m;
        if (v < 0.0) v = 0.0;
        float a = gamma[c] / sqrtf((float)v + EPS_BN);
        ab[c] = a;
        ab[OUTC + c] = beta[c] - (float)m * a;
    }
}

extern "C" void kernel_launch(void* const* d_in, const int* in_sizes, int n_in,
                              void* d_out, int out_size, void* d_ws, size_t ws_size,
                              hipStream_t stream) {
    const float* x     = (const float*)d_in[0];
    const float* gamma = (const float*)d_in[1];
    const float* beta  = (const float*)d_in[2];
    float* out = (float*)d_out;

    // Prefer 1 tile/block (12288 partial rows = 31.5 MB in ws); compile-time
    // fallback to 8 tiles/block if the workspace is small. ws_size is fixed
    // across calls -> same path every call (deterministic).
    const size_t need1 = (size_t)NTILES_TOTAL * 640 * 4 + (size_t)64 * 640 * 4 + 640 * 4;
    const int nb = (need1 <= ws_size) ? NTILES_TOTAL : (NTILES_TOTAL / 8);

    float* part1 = (float*)d_ws;                       // nb*640 floats
    float* part2 = part1 + (size_t)nb * 640;           // 64*640 floats
    float* ab    = part2 + (size_t)64 * 640;           // 640 floats

    if (nb == NTILES_TOTAL)
        fe_kernel<0, 1><<<nb, 256, 0, stream>>>(x, part1, nullptr);
    else
        fe_kernel<0, 8><<<nb, 256, 0, stream>>>(x, part1, nullptr);
    reduce1_kernel<<<64, 256, 0, stream>>>(part1, part2, nb);
    finalize_kernel<<<1, 256, 0, stream>>>(part2, gamma, beta, ab);
    fe_kernel<1, 1><<<NTILES_TOTAL, 256, 0, stream>>>(x, out, ab);
}

// Round 5
// 241.544 us; speedup vs baseline: 2.5119x; 1.5221x over previous
//
#include <hip/hip_runtime.h>

// B=8192, T=240, C=16, DAYS=STRIDE=10 -> W=24 windows tiling T exactly.
// Row r reads contiguous x[r*160 .. r*160+159]. 320 output channels:
// [corr(120), cov(120), std(16), zscore(16), ret(16), decay(16), mean(16)].
#define NROWS   196608
#define NTILES_TOTAL 12288    // 196608 rows / 16 rows-per-tile
#define OUTC    320
#define R_      16            // rows per LDS tile
#define WSTRIDE 164           // win LDS row stride (floats), float4-aligned
#define CSTRIDE 121           // cov LDS row stride
#define MSTRIDE 17            // mean/std LDS row stride
#define EPS_F   1e-8f
#define EPS_BN  1e-5f
#define RA_BLOCKS 768         // stage-A reduce grid

// pair p -> packed (i<<4)|j for triu_indices(16, k=1), row-major
__device__ const unsigned char PIJ[120] = {
    0x01,0x02,0x03,0x04,0x05,0x06,0x07,0x08,0x09,0x0A,0x0B,0x0C,0x0D,0x0E,0x0F,
    0x12,0x13,0x14,0x15,0x16,0x17,0x18,0x19,0x1A,0x1B,0x1C,0x1D,0x1E,0x1F,
    0x23,0x24,0x25,0x26,0x27,0x28,0x29,0x2A,0x2B,0x2C,0x2D,0x2E,0x2F,
    0x34,0x35,0x36,0x37,0x38,0x39,0x3A,0x3B,0x3C,0x3D,0x3E,0x3F,
    0x45,0x46,0x47,0x48,0x49,0x4A,0x4B,0x4C,0x4D,0x4E,0x4F,
    0x56,0x57,0x58,0x59,0x5A,0x5B,0x5C,0x5D,0x5E,0x5F,
    0x67,0x68,0x69,0x6A,0x6B,0x6C,0x6D,0x6E,0x6F,
    0x78,0x79,0x7A,0x7B,0x7C,0x7D,0x7E,0x7F,
    0x89,0x8A,0x8B,0x8C,0x8D,0x8E,0x8F,
    0x9A,0x9B,0x9C,0x9D,0x9E,0x9F,
    0xAB,0xAC,0xAD,0xAE,0xAF,
    0xBC,0xBD,0xBE,0xBF,
    0xCD,0xCE,0xCF,
    0xDE,0xDF,
    0xEF
};

// MODE=0: stats pass. dst = part1[block][640] (sum[320] | sumsq[320]), coalesced.
//         Processes NTILES consecutive tiles (compile-time trip count).
// MODE=1: apply pass (NTILES=1). dst = output; ab = {scale[320], shift[320]}.
template<int MODE, int NTILES>
__global__ __launch_bounds__(256)
void fe_kernel(const float* __restrict__ x, float* __restrict__ dst,
               const float* __restrict__ ab) {
    __shared__ __align__(16) float win[R_ * WSTRIDE];   // 10496 B
    __shared__ float mn[R_ * MSTRIDE];                  // 1088 B
    __shared__ float sd[R_ * MSTRIDE];                  // 1088 B
    __shared__ float cv[R_ * CSTRIDE];                  // 7744 B
    __shared__ float ex[2 * OUTC];                      // 2560 B

    const int t = threadIdx.x;

    float sacc[20], sacc2[20];
    if (MODE == 0) {
#pragma unroll
        for (int k = 0; k < 20; ++k) { sacc[k] = 0.f; sacc2[k] = 0.f; }
    } else {
        // preload scale/shift (640 floats) into LDS
        ex[t] = ab[t];
        ex[t + 256] = ab[t + 256];
        if (t < 128) ex[t + 512] = ab[t + 512];
    }

#pragma unroll 1
    for (int tt = 0; tt < NTILES; ++tt) {
        const int tile = blockIdx.x * NTILES + tt;
        const float4* src = reinterpret_cast<const float4*>(x) + (size_t)tile * (R_ * 40);

        __syncthreads();   // previous iteration readers done / ex visible
        // ---- stage 16 rows x 160 floats, coalesced float4 ----
#pragma unroll
        for (int k = 0; k < 3; ++k) {
            int q = t + k * 256;
            if (q < 640) {
                float4 v = src[q];
                int row = q / 40, pos = q % 40;
                reinterpret_cast<float4*>(win)[row * (WSTRIDE / 4) + pos] = v;
            }
        }
        __syncthreads();

        // ---- mean/std per (row, channel): 256 tasks ----
        // r = t&15 (varies fastest) -> within a wave banks hit <=2-way (free).
        {
            int r = t & 15, c = t >> 4;
            const float* wr = win + r * WSTRIDE + c;
            float s = 0.f;
#pragma unroll
            for (int d = 0; d < 10; ++d) s += wr[d * 16];
            float m = s * 0.1f;
            float v = 0.f;
#pragma unroll
            for (int d = 0; d < 10; ++d) { float dx = wr[d * 16] - m; v += dx * dx; }
            mn[r * MSTRIDE + c] = m;
            sd[r * MSTRIDE + c] = sqrtf(v * 0.1f);
        }
        __syncthreads();

        // ---- cov per (row, pair): 16*120 = 1920 tasks ----
#pragma unroll
        for (int k = 0; k < 8; ++k) {
            int task = t + k * 256;
            if (task < 1920) {
                int r = task & 15, p = task >> 4;
                int pj = PIJ[p];
                int i = pj >> 4, j = pj & 15;
                float mi = mn[r * MSTRIDE + i], mj = mn[r * MSTRIDE + j];
                const float* wr = win + r * WSTRIDE;
                float s = 0.f;
#pragma unroll
                for (int d = 0; d < 10; ++d)
                    s += (wr[d * 16 + i] - mi) * (wr[d * 16 + j] - mj);
                cv[r * CSTRIDE + p] = s * 0.1f;
            }
        }
        __syncthreads();

        // ---- outputs: 16*320 = 5120 elements, thread <-> element ----
#pragma unroll
        for (int k = 0; k < 20; ++k) {
            int flat = t + k * 256;
            int r = flat / 320, c = flat % 320;
            float v;
            if (c < 240) {
                int p = (c < 120) ? c : (c - 120);
                float cvv = cv[r * CSTRIDE + p];
                if (c < 120) {
                    int pj = PIJ[p];
                    int i = pj >> 4, j = pj & 15;
                    v = cvv / (sd[r * MSTRIDE + i] * sd[r * MSTRIDE + j] + EPS_F);
                } else {
                    v = cvv;
                }
            } else {
                int cc = c & 15;
                int cls = (c - 240) >> 4;   // 0:std 1:zscore 2:ret 3:decay 4:mean
                const float* wr = win + r * WSTRIDE + cc;
                float m = mn[r * MSTRIDE + cc], s = sd[r * MSTRIDE + cc];
                if (cls == 0)      v = s;
                else if (cls == 1) v = m / (s + EPS_F);
                else if (cls == 2) v = wr[144] / wr[0] - 1.0f;
                else if (cls == 3) {
                    float a = 0.f;
#pragma unroll
                    for (int d = 0; d < 10; ++d)
                        a += wr[d * 16] * ((float)(d + 1) * (1.0f / 55.0f));
                    v = a;
                } else v = m;
            }
            if (MODE == 1) {
                dst[(size_t)tile * (R_ * OUTC) + flat] = v * ex[c] + ex[OUTC + c];
            } else {
                sacc[k] += v;
                sacc2[k] += v * v;
            }
        }
    }

    if (MODE == 0) {
        // Per-wave LDS bins (no cross-wave races), then coalesced per-block
        // partial write part1[block][640]. Bins reuse win's LDS (free after
        // the sync; typed alias of a named array, not a carved blob).
        __syncthreads();                        // everyone done reading win
        float* bins = win;                      // 2560 floats needed, win has 2624
        for (int idx = t; idx < 2560; idx += 256) bins[idx] = 0.f;
        __syncthreads();
        float* wb = bins + (t >> 6) * 640;      // this wave's bin
#pragma unroll
        for (int k = 0; k < 20; ++k) {
            int c = (t + k * 256) % 320;        // distinct per lane within a wave
            wb[c]       += sacc[k];
            wb[c + 320] += sacc2[k];
        }
        __syncthreads();
        for (int idx = t; idx < 640; idx += 256) {
            float s = bins[idx] + bins[640 + idx] + bins[1280 + idx] + bins[1920 + idx];
            dst[(size_t)blockIdx.x * 640 + idx] = s;
        }
    }
}

// Stage-A reduce: 768 blocks; block b sums rows {b + 768*j} of part1[nb][640]
// into part2[b][640]. Row reads coalesced (lanes = consecutive v).
__global__ __launch_bounds__(256)
void reduceA_kernel(const float* __restrict__ part1, float* __restrict__ part2,
                    int nb) {
    const int rows = nb / RA_BLOCKS;            // 16 (or 2 in fallback)
    const int b = blockIdx.x;
    for (int v = threadIdx.x; v < 640; v += 256) {
        float s = 0.f;
        for (int j = 0; j < rows; ++j)
            s += part1[(size_t)(b + RA_BLOCKS * j) * 640 + v];
        part2[(size_t)b * 640 + v] = s;
    }
}

// Final: 320 blocks (one per channel). fp64 column reduce of part2[768][640]
// with a fixed-shape LDS tree (deterministic).
__global__ __launch_bounds__(256)
void finalize_kernel(const float* __restrict__ part2,
                     const float* __restrict__ gamma,
                     const float* __restrict__ beta,
                     float* __restrict__ ab) {
    __shared__ double rs[256], rs2[256];
    const int c = blockIdx.x, t = threadIdx.x;
    double s = 0.0, s2 = 0.0;
    for (int r = t; r < RA_BLOCKS; r += 256) {
        s  += (double)part2[(size_t)r * 640 + c];
        s2 += (double)part2[(size_t)r * 640 + c + OUTC];
    }
    rs[t] = s; rs2[t] = s2;
    __syncthreads();
    for (int off = 128; off; off >>= 1) {
        if (t < off) { rs[t] += rs[t + off]; rs2[t] += rs2[t + off]; }
        __syncthreads();
    }
    if (t == 0) {
        const double invN = 1.0 / (double)NROWS;
        double m = rs[0] * invN;
        double v = rs2[0] * invN - m * m;
        if (v < 0.0) v = 0.0;
        float a = gamma[c] / sqrtf((float)v + EPS_BN);
        ab[c] = a;
        ab[OUTC + c] = beta[c] - (float)m * a;
    }
}

extern "C" void kernel_launch(void* const* d_in, const int* in_sizes, int n_in,
                              void* d_out, int out_size, void* d_ws, size_t ws_size,
                              hipStream_t stream) {
    const float* x     = (const float*)d_in[0];
    const float* gamma = (const float*)d_in[1];
    const float* beta  = (const float*)d_in[2];
    float* out = (float*)d_out;

    // Prefer 1 tile/block (12288 partial rows = 31.5 MB in ws); compile-time
    // fallback to 8 tiles/block if the workspace is small. ws_size is fixed
    // across calls -> same path every call (deterministic).
    const size_t need1 = (size_t)NTILES_TOTAL * 640 * 4
                       + (size_t)RA_BLOCKS * 640 * 4 + 640 * 4;
    const int nb = (need1 <= ws_size) ? NTILES_TOTAL : (NTILES_TOTAL / 8);

    float* part1 = (float*)d_ws;                       // nb*640 floats
    float* part2 = part1 + (size_t)nb * 640;           // 768*640 floats
    float* ab    = part2 + (size_t)RA_BLOCKS * 640;    // 640 floats

    if (nb == NTILES_TOTAL)
        fe_kernel<0, 1><<<nb, 256, 0, stream>>>(x, part1, nullptr);
    else
        fe_kernel<0, 8><<<nb, 256, 0, stream>>>(x, part1, nullptr);
    reduceA_kernel<<<RA_BLOCKS, 256, 0, stream>>>(part1, part2, nb);
    finalize_kernel<<<OUTC, 256, 0, stream>>>(part2, gamma, beta, ab);
    fe_kernel<1, 1><<<NTILES_TOTAL, 256, 0, stream>>>(x, out, ab);
}

// Round 6
// 187.489 us; speedup vs baseline: 3.2362x; 1.2883x over previous
//
#include <hip/hip_runtime.h>

// B=8192, T=240, C=16, DAYS=STRIDE=10 -> W=24 windows tiling T exactly.
// Row r reads contiguous x[r*160 .. r*160+159]. 320 output channels:
// [corr(120), cov(120), std(16), zscore(16), ret(16), decay(16), mean(16)].
#define NROWS   196608
#define NTILES_TOTAL 12288    // 196608 rows / 16 rows-per-tile
#define OUTC    320
#define R_      16            // rows per LDS tile
#define WSTRIDE 164           // win LDS row stride (floats), float4-aligned
#define CSTRIDE 121           // cov LDS row stride
#define MSTRIDE 17            // mean/std LDS row stride
#define EPS_F   1e-8f
#define EPS_BN  1e-5f
#define RA_BLOCKS 768         // stage-A reduce grid

// pair p -> packed (i<<4)|j for triu_indices(16, k=1), row-major
__device__ const unsigned char PIJ[120] = {
    0x01,0x02,0x03,0x04,0x05,0x06,0x07,0x08,0x09,0x0A,0x0B,0x0C,0x0D,0x0E,0x0F,
    0x12,0x13,0x14,0x15,0x16,0x17,0x18,0x19,0x1A,0x1B,0x1C,0x1D,0x1E,0x1F,
    0x23,0x24,0x25,0x26,0x27,0x28,0x29,0x2A,0x2B,0x2C,0x2D,0x2E,0x2F,
    0x34,0x35,0x36,0x37,0x38,0x39,0x3A,0x3B,0x3C,0x3D,0x3E,0x3F,
    0x45,0x46,0x47,0x48,0x49,0x4A,0x4B,0x4C,0x4D,0x4E,0x4F,
    0x56,0x57,0x58,0x59,0x5A,0x5B,0x5C,0x5D,0x5E,0x5F,
    0x67,0x68,0x69,0x6A,0x6B,0x6C,0x6D,0x6E,0x6F,
    0x78,0x79,0x7A,0x7B,0x7C,0x7D,0x7E,0x7F,
    0x89,0x8A,0x8B,0x8C,0x8D,0x8E,0x8F,
    0x9A,0x9B,0x9C,0x9D,0x9E,0x9F,
    0xAB,0xAC,0xAD,0xAE,0xAF,
    0xBC,0xBD,0xBE,0xBF,
    0xCD,0xCE,0xCF,
    0xDE,0xDF,
    0xEF
};

// 320 threads/block (5 waves). Thread t owns OUTPUT CHANNEL t for all 16
// rows of the tile -> MODE=0 accumulator is 2 scalar registers and the
// partial write is 2 coalesced stores (no bin tail, no extra syncs).
// MODE=0: dst = part1[block][640] (sum[320] | sumsq[320]).
// MODE=1: dst = output; ab = {scale[320], shift[320]} read into registers.
template<int MODE, int NTILES>
__global__ __launch_bounds__(320)
void fe_kernel(const float* __restrict__ x, float* __restrict__ dst,
               const float* __restrict__ ab) {
    __shared__ __align__(16) float win[R_ * WSTRIDE];   // 10496 B
    __shared__ float mn[R_ * MSTRIDE];                  // 1088 B
    __shared__ float sd[R_ * MSTRIDE];                  // 1088 B
    __shared__ float cv[R_ * CSTRIDE];                  // 7744 B

    const int t = threadIdx.x;      // 0..319 == output channel

    // ---- per-thread channel invariants (computed once) ----
    const int c = t;
    int pi = 0, pj = 0, pp = 0;
    if (c < 240) {
        pp = (c < 120) ? c : (c - 120);
        int b = PIJ[pp];
        pi = b >> 4; pj = b & 15;
    }
    const int cc  = c & 15;
    const int cls = (c - 240) >> 4;   // valid only for c>=240: 0..4

    float scale = 0.f, shift = 0.f;
    if (MODE == 1) { scale = ab[c]; shift = ab[c + OUTC]; }

    float acc = 0.f, acc2 = 0.f;

#pragma unroll 1
    for (int tt = 0; tt < NTILES; ++tt) {
        const int tile = blockIdx.x * NTILES + tt;
        const float4* src = reinterpret_cast<const float4*>(x) + (size_t)tile * 640;

        __syncthreads();   // previous iteration readers done
        // ---- stage 16 rows x 160 floats: 640 float4, 2 per thread ----
#pragma unroll
        for (int k = 0; k < 2; ++k) {
            int q = t + k * 320;
            float4 v = src[q];
            int row = q / 40, pos = q % 40;
            reinterpret_cast<float4*>(win)[row * (WSTRIDE / 4) + pos] = v;
        }
        __syncthreads();

        // ---- mean/std per (row, channel): 256 tasks, r fastest ----
        if (t < 256) {
            int r = t & 15, ch = t >> 4;
            const float* wr = win + r * WSTRIDE + ch;
            float s = 0.f;
#pragma unroll
            for (int d = 0; d < 10; ++d) s += wr[d * 16];
            float m = s * 0.1f;
            float v = 0.f;
#pragma unroll
            for (int d = 0; d < 10; ++d) { float dx = wr[d * 16] - m; v += dx * dx; }
            mn[r * MSTRIDE + ch] = m;
            sd[r * MSTRIDE + ch] = sqrtf(v * 0.1f);
        }
        __syncthreads();

        // ---- cov: 1920 tasks = 320 x 6, p fastest (i-reads broadcast,
        //      j-reads consecutive -> near conflict-free) ----
#pragma unroll
        for (int k = 0; k < 6; ++k) {
            int task = t + k * 320;
            int r = task / 120, p = task - r * 120;
            int b = PIJ[p];
            int i = b >> 4, j = b & 15;
            float mi = mn[r * MSTRIDE + i], mj = mn[r * MSTRIDE + j];
            const float* wr = win + r * WSTRIDE;
            float s = 0.f;
#pragma unroll
            for (int d = 0; d < 10; ++d)
                s += (wr[d * 16 + i] - mi) * (wr[d * 16 + j] - mj);
            cv[r * CSTRIDE + p] = s * 0.1f;
        }
        __syncthreads();

        // ---- outputs: thread t = channel t, iterate 16 rows ----
#pragma unroll
        for (int r = 0; r < R_; ++r) {
            float v;
            if (c < 120) {
                v = cv[r * CSTRIDE + pp]
                  / (sd[r * MSTRIDE + pi] * sd[r * MSTRIDE + pj] + EPS_F);
            } else if (c < 240) {
                v = cv[r * CSTRIDE + pp];
            } else {
                const float* wr = win + r * WSTRIDE + cc;
                float m = mn[r * MSTRIDE + cc], s = sd[r * MSTRIDE + cc];
                if (cls == 0)      v = s;
                else if (cls == 1) v = m / (s + EPS_F);
                else if (cls == 2) v = wr[144] / wr[0] - 1.0f;
                else if (cls == 3) {
                    float a = 0.f;
#pragma unroll
                    for (int d = 0; d < 10; ++d)
                        a += wr[d * 16] * ((float)(d + 1) * (1.0f / 55.0f));
                    v = a;
                } else v = m;
            }
            if (MODE == 1) {
                dst[(size_t)tile * (R_ * OUTC) + r * OUTC + c] = v * scale + shift;
            } else {
                acc += v;
                acc2 += v * v;
            }
        }
    }

    if (MODE == 0) {
        dst[(size_t)blockIdx.x * 640 + t]        = acc;
        dst[(size_t)blockIdx.x * 640 + OUTC + t] = acc2;
    }
}

// Stage-A reduce: 768 blocks; block b sums rows {b + 768*j} of part1[nb][640]
// into part2[b][640]. Row reads coalesced (lanes = consecutive v).
__global__ __launch_bounds__(256)
void reduceA_kernel(const float* __restrict__ part1, float* __restrict__ part2,
                    int nb) {
    const int rows = nb / RA_BLOCKS;            // 16 (or 2 in fallback)
    const int b = blockIdx.x;
    for (int v = threadIdx.x; v < 640; v += 256) {
        float s = 0.f;
        for (int j = 0; j < rows; ++j)
            s += part1[(size_t)(b + RA_BLOCKS * j) * 640 + v];
        part2[(size_t)b * 640 + v] = s;
    }
}

// Final: 320 blocks (one per channel). fp64 column reduce of part2[768][640]
// with a fixed-shape LDS tree (deterministic).
__global__ __launch_bounds__(256)
void finalize_kernel(const float* __restrict__ part2,
                     const float* __restrict__ gamma,
                     const float* __restrict__ beta,
                     float* __restrict__ ab) {
    __shared__ double rs[256], rs2[256];
    const int c = blockIdx.x, t = threadIdx.x;
    double s = 0.0, s2 = 0.0;
    for (int r = t; r < RA_BLOCKS; r += 256) {
        s  += (double)part2[(size_t)r * 640 + c];
        s2 += (double)part2[(size_t)r * 640 + c + OUTC];
    }
    rs[t] = s; rs2[t] = s2;
    __syncthreads();
    for (int off = 128; off; off >>= 1) {
        if (t < off) { rs[t] += rs[t + off]; rs2[t] += rs2[t + off]; }
        __syncthreads();
    }
    if (t == 0) {
        const double invN = 1.0 / (double)NROWS;
        double m = rs[0] * invN;
        double v = rs2[0] * invN - m * m;
        if (v < 0.0) v = 0.0;
        float a = gamma[c] / sqrtf((float)v + EPS_BN);
        ab[c] = a;
        ab[OUTC + c] = beta[c] - (float)m * a;
    }
}

extern "C" void kernel_launch(void* const* d_in, const int* in_sizes, int n_in,
                              void* d_out, int out_size, void* d_ws, size_t ws_size,
                              hipStream_t stream) {
    const float* x     = (const float*)d_in[0];
    const float* gamma = (const float*)d_in[1];
    const float* beta  = (const float*)d_in[2];
    float* out = (float*)d_out;

    // Prefer 1 tile/block for stats (12288 partial rows = 31.5 MB in ws);
    // compile-time fallback to 8 tiles/block if ws is small. ws_size is
    // fixed across calls -> same path every call (deterministic).
    const size_t need1 = (size_t)NTILES_TOTAL * 640 * 4
                       + (size_t)RA_BLOCKS * 640 * 4 + 640 * 4;
    const int nb = (need1 <= ws_size) ? NTILES_TOTAL : (NTILES_TOTAL / 8);

    float* part1 = (float*)d_ws;                       // nb*640 floats
    float* part2 = part1 + (size_t)nb * 640;           // 768*640 floats
    float* ab    = part2 + (size_t)RA_BLOCKS * 640;    // 640 floats

    if (nb == NTILES_TOTAL)
        fe_kernel<0, 1><<<nb, 320, 0, stream>>>(x, part1, nullptr);
    else
        fe_kernel<0, 8><<<nb, 320, 0, stream>>>(x, part1, nullptr);
    reduceA_kernel<<<RA_BLOCKS, 256, 0, stream>>>(part1, part2, nb);
    finalize_kernel<<<OUTC, 256, 0, stream>>>(part2, gamma, beta, ab);
    fe_kernel<1, 1><<<NTILES_TOTAL, 320, 0, stream>>>(x, out, ab);
}

// Round 7
// 129.128 us; speedup vs baseline: 4.6988x; 1.4520x over previous
//
#include <hip/hip_runtime.h>

// B=8192, T=240, C=16, DAYS=STRIDE=10 -> W=24 windows tiling T exactly.
// Row r reads contiguous x[r*160 .. r*160+159]. 320 output channels:
// [corr(120), cov(120), std(16), zscore(16), ret(16), decay(16), mean(16)].
#define NROWS   196608
#define NTILES_TOTAL 12288    // 196608 rows / 16 rows-per-tile
#define OUTC    320
#define R_      16            // rows per LDS tile
#define WSTRIDE 164           // win LDS row stride (floats), float4-aligned
#define CV_S    20            // cv2 [pair][row] stride (floats), 16B-aligned
#define FB_S    20            // featB [chan][row] stride (floats), 16B-aligned
#define EPS_F   1e-8f
#define EPS_BN  1e-5f
#define RA_BLOCKS 768         // stage-A reduce grid

// pair p -> packed (i<<4)|j for triu_indices(16, k=1), row-major
__device__ const unsigned char PIJ[120] = {
    0x01,0x02,0x03,0x04,0x05,0x06,0x07,0x08,0x09,0x0A,0x0B,0x0C,0x0D,0x0E,0x0F,
    0x12,0x13,0x14,0x15,0x16,0x17,0x18,0x19,0x1A,0x1B,0x1C,0x1D,0x1E,0x1F,
    0x23,0x24,0x25,0x26,0x27,0x28,0x29,0x2A,0x2B,0x2C,0x2D,0x2E,0x2F,
    0x34,0x35,0x36,0x37,0x38,0x39,0x3A,0x3B,0x3C,0x3D,0x3E,0x3F,
    0x45,0x46,0x47,0x48,0x49,0x4A,0x4B,0x4C,0x4D,0x4E,0x4F,
    0x56,0x57,0x58,0x59,0x5A,0x5B,0x5C,0x5D,0x5E,0x5F,
    0x67,0x68,0x69,0x6A,0x6B,0x6C,0x6D,0x6E,0x6F,
    0x78,0x79,0x7A,0x7B,0x7C,0x7D,0x7E,0x7F,
    0x89,0x8A,0x8B,0x8C,0x8D,0x8E,0x8F,
    0x9A,0x9B,0x9C,0x9D,0x9E,0x9F,
    0xAB,0xAC,0xAD,0xAE,0xAF,
    0xBC,0xBD,0xBE,0xBF,
    0xCD,0xCE,0xCF,
    0xDE,0xDF,
    0xEF
};

// p(i,j) for i<j, row-major triu: p = i*15 - i(i-1)/2 + j - i - 1
__device__ __forceinline__ int pair_idx(int i, int j) {
    return i * 15 - (i * (i - 1)) / 2 + j - i - 1;
}

// 320 threads/block (5 waves). Thread t owns OUTPUT CHANNEL t.
// Phase 2 (single sync): threads 0..159 = Gram 4x4 register blocks (b128
// column reads, raw products); threads 256..319 = per-(row, chan-quad)
// mean/std/z/ret/decay -> featB [chan][row].
// MODE=0: dst = part1[block][640] (sum[320] | sumsq[320]).
// MODE=1: dst = output; ab = {scale[320], shift[320]} in registers.
template<int MODE, int NTILES>
__global__ __launch_bounds__(320)
void fe_kernel(const float* __restrict__ x, float* __restrict__ dst,
               const float* __restrict__ ab) {
    __shared__ __align__(16) float win[R_ * WSTRIDE];     // 10496 B
    __shared__ __align__(16) float cv2[120 * CV_S];       //  9600 B  g=E[xi*xj], [p][r]
    __shared__ __align__(16) float featB[80 * FB_S];      //  6400 B  [c-240][r]

    const int t = threadIdx.x;      // 0..319 == output channel

    // ---- per-thread channel invariants ----
    const int c = t;
    int pi = 0, pj = 0, pp = 0;
    if (c < 240) {
        pp = (c < 120) ? c : (c - 120);
        int b = PIJ[pp];
        pi = b >> 4; pj = b & 15;
    }
    const int c2 = c - 240;

    float scale = 0.f, shift = 0.f;
    if (MODE == 1) { scale = ab[c]; shift = ab[c + OUTC]; }

    float acc = 0.f, acc2 = 0.f;

#pragma unroll 1
    for (int tt = 0; tt < NTILES; ++tt) {
        const int tile = blockIdx.x * NTILES + tt;
        const float4* src = reinterpret_cast<const float4*>(x) + (size_t)tile * 640;

        __syncthreads();   // previous iteration readers done
        // ---- stage 16 rows x 160 floats: 640 float4, 2 per thread ----
#pragma unroll
        for (int k = 0; k < 2; ++k) {
            int q = t + k * 320;
            float4 v = src[q];
            int row = q / 40, pos = q % 40;
            reinterpret_cast<float4*>(win)[row * (WSTRIDE / 4) + pos] = v;
        }
        __syncthreads();

        // ---- phase 2: Gram (t<160) || scalar families (t>=256) ----
        if (t < 160) {
            const int r = t & 15, q = t >> 4;   // q = 0..9
            const float* wr = win + r * WSTRIDE;
            if (q < 6) {
                // off-diagonal 4x4 block
                const int i0 = (q < 3) ? 0 : ((q < 5) ? 4 : 8);
                const int j0 = (q == 0) ? 4 : ((q == 1 || q == 3) ? 8 : 12);
                float gacc[4][4];
#pragma unroll
                for (int a = 0; a < 4; ++a)
#pragma unroll
                    for (int b = 0; b < 4; ++b) gacc[a][b] = 0.f;
#pragma unroll
                for (int d = 0; d < 10; ++d) {
                    float4 vi = *reinterpret_cast<const float4*>(wr + d * 16 + i0);
                    float4 vj = *reinterpret_cast<const float4*>(wr + d * 16 + j0);
                    float ai[4] = {vi.x, vi.y, vi.z, vi.w};
                    float aj[4] = {vj.x, vj.y, vj.z, vj.w};
#pragma unroll
                    for (int a = 0; a < 4; ++a)
#pragma unroll
                        for (int b = 0; b < 4; ++b)
                            gacc[a][b] += ai[a] * aj[b];
                }
#pragma unroll
                for (int a = 0; a < 4; ++a) {
                    int i = i0 + a;
                    int base = i * 15 - (i * (i - 1)) / 2 - i - 1;
#pragma unroll
                    for (int b = 0; b < 4; ++b)
                        cv2[(base + j0 + b) * CV_S + r] = gacc[a][b] * 0.1f;
                }
            } else {
                // diagonal 4x4 block: 6 upper pairs
                const int i0 = (q - 6) << 2;
                float g01 = 0.f, g02 = 0.f, g03 = 0.f,
                      g12 = 0.f, g13 = 0.f, g23 = 0.f;
#pragma unroll
                for (int d = 0; d < 10; ++d) {
                    float4 vi = *reinterpret_cast<const float4*>(wr + d * 16 + i0);
                    float a0 = vi.x, a1 = vi.y, a2 = vi.z, a3 = vi.w;
                    g01 += a0 * a1; g02 += a0 * a2; g03 += a0 * a3;
                    g12 += a1 * a2; g13 += a1 * a3; g23 += a2 * a3;
                }
                cv2[pair_idx(i0 + 0, i0 + 1) * CV_S + r] = g01 * 0.1f;
                cv2[pair_idx(i0 + 0, i0 + 2) * CV_S + r] = g02 * 0.1f;
                cv2[pair_idx(i0 + 0, i0 + 3) * CV_S + r] = g03 * 0.1f;
                cv2[pair_idx(i0 + 1, i0 + 2) * CV_S + r] = g12 * 0.1f;
                cv2[pair_idx(i0 + 1, i0 + 3) * CV_S + r] = g13 * 0.1f;
                cv2[pair_idx(i0 + 2, i0 + 3) * CV_S + r] = g23 * 0.1f;
            }
        } else if (t >= 256) {
            const int lane = t - 256;                 // 0..63
            const int r = lane & 15;
            const int c0 = (lane >> 4) << 2;          // 0,4,8,12
            const float* wr = win + r * WSTRIDE + c0;
            float sm[4], sq[4], dec[4], first[4], last[4];
#pragma unroll
            for (int k = 0; k < 4; ++k) { sm[k] = 0.f; sq[k] = 0.f; dec[k] = 0.f; }
#pragma unroll
            for (int d = 0; d < 10; ++d) {
                float4 v = *reinterpret_cast<const float4*>(wr + d * 16);
                float a[4] = {v.x, v.y, v.z, v.w};
#pragma unroll
                for (int k = 0; k < 4; ++k) {
                    sm[k] += a[k];
                    sq[k] += a[k] * a[k];
                    dec[k] += a[k] * (float)(d + 1);
                    if (d == 0) first[k] = a[k];
                    if (d == 9) last[k]  = a[k];
                }
            }
#pragma unroll
            for (int k = 0; k < 4; ++k) {
                int ch = c0 + k;
                float m = sm[k] * 0.1f;
                float var = fmaxf(sq[k] * 0.1f - m * m, 0.f);
                float s = sqrtf(var);
                featB[(0 * 16 + ch) * FB_S + r] = s;                       // std
                featB[(1 * 16 + ch) * FB_S + r] = m / (s + EPS_F);         // zscore
                featB[(2 * 16 + ch) * FB_S + r] = last[k] / first[k] - 1.f;// ret
                featB[(3 * 16 + ch) * FB_S + r] = dec[k] * (1.f / 55.f);   // decay
                featB[(4 * 16 + ch) * FB_S + r] = m;                       // mean
            }
        }
        __syncthreads();

        // ---- outputs: thread t = channel c, 16 rows in float4 chunks ----
#pragma unroll
        for (int rb4 = 0; rb4 < 4; ++rb4) {
            const int rb = rb4 * 4;
            float vals[4];
            if (c < 240) {
                float4 g4  = *reinterpret_cast<const float4*>(cv2 + pp * CV_S + rb);
                float4 mi4 = *reinterpret_cast<const float4*>(featB + (64 + pi) * FB_S + rb);
                float4 mj4 = *reinterpret_cast<const float4*>(featB + (64 + pj) * FB_S + rb);
                float g[4]  = {g4.x, g4.y, g4.z, g4.w};
                float mi[4] = {mi4.x, mi4.y, mi4.z, mi4.w};
                float mj[4] = {mj4.x, mj4.y, mj4.z, mj4.w};
                if (c < 120) {
                    float4 si4 = *reinterpret_cast<const float4*>(featB + pi * FB_S + rb);
                    float4 sj4 = *reinterpret_cast<const float4*>(featB + pj * FB_S + rb);
                    float si[4] = {si4.x, si4.y, si4.z, si4.w};
                    float sj[4] = {sj4.x, sj4.y, sj4.z, sj4.w};
#pragma unroll
                    for (int k = 0; k < 4; ++k)
                        vals[k] = (g[k] - mi[k] * mj[k]) / (si[k] * sj[k] + EPS_F);
                } else {
#pragma unroll
                    for (int k = 0; k < 4; ++k)
                        vals[k] = g[k] - mi[k] * mj[k];
                }
            } else {
                float4 f4 = *reinterpret_cast<const float4*>(featB + c2 * FB_S + rb);
                vals[0] = f4.x; vals[1] = f4.y; vals[2] = f4.z; vals[3] = f4.w;
            }
#pragma unroll
            for (int k = 0; k < 4; ++k) {
                if (MODE == 1) {
                    dst[(size_t)tile * (R_ * OUTC) + (rb + k) * OUTC + c]
                        = vals[k] * scale + shift;
                } else {
                    acc += vals[k];
                    acc2 += vals[k] * vals[k];
                }
            }
        }
    }

    if (MODE == 0) {
        dst[(size_t)blockIdx.x * 640 + t]        = acc;
        dst[(size_t)blockIdx.x * 640 + OUTC + t] = acc2;
    }
}

// Stage-A reduce: 768 blocks; block b sums rows {b + 768*j} of part1[nb][640]
// into part2[b][640]. Row reads coalesced (lanes = consecutive v).
__global__ __launch_bounds__(256)
void reduceA_kernel(const float* __restrict__ part1, float* __restrict__ part2,
                    int nb) {
    const int rows = nb / RA_BLOCKS;            // 16 (or 2 in fallback)
    const int b = blockIdx.x;
    for (int v = threadIdx.x; v < 640; v += 256) {
        float s = 0.f;
        for (int j = 0; j < rows; ++j)
            s += part1[(size_t)(b + RA_BLOCKS * j) * 640 + v];
        part2[(size_t)b * 640 + v] = s;
    }
}

// Final: 320 blocks (one per channel). fp64 column reduce of part2[768][640]
// with a fixed-shape LDS tree (deterministic).
__global__ __launch_bounds__(256)
void finalize_kernel(const float* __restrict__ part2,
                     const float* __restrict__ gamma,
                     const float* __restrict__ beta,
                     float* __restrict__ ab) {
    __shared__ double rs[256], rs2[256];
    const int c = blockIdx.x, t = threadIdx.x;
    double s = 0.0, s2 = 0.0;
    for (int r = t; r < RA_BLOCKS; r += 256) {
        s  += (double)part2[(size_t)r * 640 + c];
        s2 += (double)part2[(size_t)r * 640 + c + OUTC];
    }
    rs[t] = s; rs2[t] = s2;
    __syncthreads();
    for (int off = 128; off; off >>= 1) {
        if (t < off) { rs[t] += rs[t + off]; rs2[t] += rs2[t + off]; }
        __syncthreads();
    }
    if (t == 0) {
        const double invN = 1.0 / (double)NROWS;
        double m = rs[0] * invN;
        double v = rs2[0] * invN - m * m;
        if (v < 0.0) v = 0.0;
        float a = gamma[c] / sqrtf((float)v + EPS_BN);
        ab[c] = a;
        ab[OUTC + c] = beta[c] - (float)m * a;
    }
}

extern "C" void kernel_launch(void* const* d_in, const int* in_sizes, int n_in,
                              void* d_out, int out_size, void* d_ws, size_t ws_size,
                              hipStream_t stream) {
    const float* x     = (const float*)d_in[0];
    const float* gamma = (const float*)d_in[1];
    const float* beta  = (const float*)d_in[2];
    float* out = (float*)d_out;

    // Prefer 1 tile/block for stats (12288 partial rows = 31.5 MB in ws);
    // compile-time fallback to 8 tiles/block if ws is small. ws_size is
    // fixed across calls -> same path every call (deterministic).
    const size_t need1 = (size_t)NTILES_TOTAL * 640 * 4
                       + (size_t)RA_BLOCKS * 640 * 4 + 640 * 4;
    const int nb = (need1 <= ws_size) ? NTILES_TOTAL : (NTILES_TOTAL / 8);

    float* part1 = (float*)d_ws;                       // nb*640 floats
    float* part2 = part1 + (size_t)nb * 640;           // 768*640 floats
    float* ab    = part2 + (size_t)RA_BLOCKS * 640;    // 640 floats

    if (nb == NTILES_TOTAL)
        fe_kernel<0, 1><<<nb, 320, 0, stream>>>(x, part1, nullptr);
    else
        fe_kernel<0, 8><<<nb, 320, 0, stream>>>(x, part1, nullptr);
    reduceA_kernel<<<RA_BLOCKS, 256, 0, stream>>>(part1, part2, nb);
    finalize_kernel<<<OUTC, 256, 0, stream>>>(part2, gamma, beta, ab);
    fe_kernel<1, 1><<<NTILES_TOTAL, 320, 0, stream>>>(x, out, ab);
}